// Round 1
// baseline (1253.810 us; speedup 1.0000x reference)
//
#include <hip/hip_runtime.h>
#include <cstdint>

#define NH 8
#define HD 96
#define CDIM 768
#define BQ 2
#define T0 8
#define H0 56
#define W0 56
#define L0 (T0*H0*W0)    // 25088
#define HP_Q 28
#define WP_Q 28
#define LQ (T0*HP_Q*WP_Q) // 6272
#define HP_K 7
#define WP_K 7
#define LK (T0*HP_K*WP_K) // 392

typedef __bf16 bf16;
typedef bf16 bf16x4 __attribute__((ext_vector_type(4)));
typedef bf16 bf16x8 __attribute__((ext_vector_type(8)));
typedef float f32x4 __attribute__((ext_vector_type(4)));
typedef float f4 __attribute__((ext_vector_type(4)));

// ---------------- fp32 -> bf16 conversion ----------------
__global__ void cvt4(const f4* __restrict__ in, bf16x4* __restrict__ out, long n4) {
    long i = (long)blockIdx.x * blockDim.x + threadIdx.x;
    long stride = (long)gridDim.x * blockDim.x;
    for (; i < n4; i += stride) {
        f4 v = in[i];
        bf16x4 o;
        o.x = (bf16)v.x; o.y = (bf16)v.y; o.z = (bf16)v.z; o.w = (bf16)v.w;
        out[i] = o;
    }
}

// ---------------- MFMA GEMM: out[m,n] = sum_k A[m,k]*B[n,k] + bias[n] ----------------
// MODE 0: epilogue = GELU, scatter bf16 to [b*NH+nh][L0][HD]  (qkv part, N=768)
// MODE 1: epilogue = fp32 write to Out[m*N + n]                (proj)
template<int MODE>
__global__ __launch_bounds__(256) void gemm_bt(
    const bf16* __restrict__ A, const bf16* __restrict__ B,
    const float* __restrict__ bias, void* __restrict__ Out,
    int M, int N, int K)
{
    __shared__ bf16 As[128*32];
    __shared__ bf16 Bs[128*32];
    const int tid = threadIdx.x;
    const int lane = tid & 63;
    const int w = tid >> 6;
    const int wr = w >> 1, wc = w & 1;
    const long bm = blockIdx.x, bn = blockIdx.y;

    f32x4 acc[4][4];
#pragma unroll
    for (int i = 0; i < 4; ++i)
#pragma unroll
        for (int j = 0; j < 4; ++j) acc[i][j] = (f32x4){0.f,0.f,0.f,0.f};

    const int lrow = tid >> 2;        // 0..63
    const int lcol = (tid & 3) * 8;   // 0,8,16,24
    const bf16* Ag = A + (bm*128 + lrow)*(long)K + lcol;
    const bf16* Bg = B + (bn*128 + lrow)*(long)K + lcol;
    bf16* As0 = &As[lrow*32 + lcol];
    bf16* As1 = &As[(lrow+64)*32 + lcol];
    bf16* Bs0 = &Bs[lrow*32 + lcol];
    bf16* Bs1 = &Bs[(lrow+64)*32 + lcol];
    const int arow = lane & 15;
    const int akol = (lane >> 4) * 8;

    const int nkt = K / 32;
    for (int kt = 0; kt < nkt; ++kt) {
        __syncthreads();
        *(bf16x8*)As0 = *(const bf16x8*)(Ag);
        *(bf16x8*)As1 = *(const bf16x8*)(Ag + 64l*K);
        *(bf16x8*)Bs0 = *(const bf16x8*)(Bg);
        *(bf16x8*)Bs1 = *(const bf16x8*)(Bg + 64l*K);
        Ag += 32; Bg += 32;
        __syncthreads();
        bf16x8 af[4], bfr[4];
#pragma unroll
        for (int i = 0; i < 4; ++i) {
            af[i]  = *(const bf16x8*)&As[(wr*64 + i*16 + arow)*32 + akol];
            bfr[i] = *(const bf16x8*)&Bs[(wc*64 + i*16 + arow)*32 + akol];
        }
#pragma unroll
        for (int i = 0; i < 4; ++i)
#pragma unroll
            for (int j = 0; j < 4; ++j)
                acc[i][j] = __builtin_amdgcn_mfma_f32_16x16x32_bf16(af[i], bfr[j], acc[i][j], 0, 0, 0);
    }

    // epilogue: C/D layout col = lane&15, row = (lane>>4)*4 + r   [learn_hip m89]
#pragma unroll
    for (int i = 0; i < 4; ++i) {
        int row0 = (int)bm*128 + wr*64 + i*16 + ((lane>>4)<<2);
#pragma unroll
        for (int j = 0; j < 4; ++j) {
            int col = (int)bn*128 + wc*64 + j*16 + (lane & 15);
            float bcol = bias[col];
#pragma unroll
            for (int r = 0; r < 4; ++r) {
                float vacc = acc[i][j][r] + bcol;
                int m = row0 + r;
                if (MODE == 0) {
                    float g = 0.5f * vacc * (1.0f + erff(vacc * 0.7071067811865476f));
                    int b = m / L0, l = m % L0;
                    int nh = col / HD, c = col % HD;
                    ((bf16*)Out)[(((size_t)(b*NH + nh))*L0 + l)*HD + c] = (bf16)g;
                } else {
                    ((float*)Out)[(size_t)m*N + col] = vacc;
                }
            }
        }
    }
}

// ---------------- depthwise conv3d (k=3, pad=1, stride (1,ST,ST)) ----------------
// in: [16][L0][96] bf16 (already GELU'd), w: [96][27] f32, out: [16][T0*HP*WP][96] f32
template<int ST, int HP, int WP>
__global__ __launch_bounds__(256) void dwconv(
    const bf16* __restrict__ in, const float* __restrict__ w,
    float* __restrict__ out, int total)
{
    __shared__ float lw[27*HD];
    for (int i = threadIdx.x; i < 27*HD; i += 256) {
        int c = i / 27, tap = i % 27;
        lw[tap*HD + c] = w[i];
    }
    __syncthreads();
    int idx = blockIdx.x*256 + threadIdx.x;
    if (idx >= total) return;
    int c = idx % HD;
    int r = idx / HD;
    int xo = r % WP; r /= WP;
    int yo = r % HP; r /= HP;
    int to = r % T0;
    int bh = r / T0;
    const bf16* ip = in + (size_t)bh * L0 * HD;
    float acc = 0.f;
#pragma unroll
    for (int dt = 0; dt < 3; ++dt) {
        int t = to + dt - 1;
        if (t < 0 || t >= T0) continue;
#pragma unroll
        for (int dy = 0; dy < 3; ++dy) {
            int y = yo*ST + dy - 1;
            if (y < 0 || y >= H0) continue;
#pragma unroll
            for (int dx = 0; dx < 3; ++dx) {
                int x = xo*ST + dx - 1;
                if (x < 0 || x >= W0) continue;
                float val = (float)ip[((size_t)((t*H0 + y)*W0 + x))*HD + c];
                acc += lw[(dt*9 + dy*3 + dx)*HD + c] * val;
            }
        }
    }
    out[idx] = acc;
}

// ---------------- attention: 32 q-rows per block, full 392 kv ----------------
__global__ __launch_bounds__(256) void attn_kernel(
    const float* __restrict__ q,   // [16][LQ][96]
    const float* __restrict__ k,   // [16][LK][96]
    const float* __restrict__ v,   // [16][LK][96]
    bf16* __restrict__ out)        // [B][LQ][768]
{
    __shared__ float qt[HD*32];    // [c][qi]
    __shared__ float st[LK*32];    // [j][qi]
    __shared__ float inv_d[32];
    int blk = blockIdx.x;
    int qblk = blk % (LQ/32);
    int bh = blk / (LQ/32);
    int qbase = qblk * 32;
    const float* qp = q + ((size_t)bh*LQ + qbase)*HD;
    const float* kp = k + (size_t)bh*LK*HD;
    const float* vp = v + (size_t)bh*LK*HD;
    int tid = threadIdx.x;

    for (int i = tid; i < 32*HD; i += 256) {
        int qi = i / HD, c = i % HD;
        qt[c*32 + qi] = qp[(size_t)qi*HD + c];
    }
    __syncthreads();

    // scores: each thread owns kv-row j, accumulates against 32 q rows
    const float scale = 0.10206207261596577f;  // 96^-0.5
    for (int j = tid; j < LK; j += 256) {
        float sc[32];
#pragma unroll
        for (int qi = 0; qi < 32; ++qi) sc[qi] = 0.f;
        const float* kr = kp + (size_t)j*HD;
        for (int c = 0; c < HD; ++c) {
            float kv = kr[c];
#pragma unroll
            for (int qi = 0; qi < 32; ++qi) sc[qi] += qt[c*32 + qi] * kv;
        }
#pragma unroll
        for (int qi = 0; qi < 32; ++qi) st[j*32 + qi] = sc[qi] * scale;
    }
    __syncthreads();

    // softmax per q-row (leave p unnormalized, keep 1/sum)
    if (tid < 32) {
        int qi = tid;
        float mx = -1e30f;
        for (int j = 0; j < LK; ++j) mx = fmaxf(mx, st[j*32 + qi]);
        float sum = 0.f;
        for (int j = 0; j < LK; ++j) {
            float p = __expf(st[j*32 + qi] - mx);
            st[j*32 + qi] = p;
            sum += p;
        }
        inv_d[qi] = 1.0f / sum;
    }
    __syncthreads();

    // out: thread -> (c, sub); sub selects 16 q-rows
    if (tid < 192) {
        int c = tid % HD;
        int sub = tid / HD;
        float acc[16];
#pragma unroll
        for (int i = 0; i < 16; ++i) acc[i] = 0.f;
        for (int j = 0; j < LK; ++j) {
            float vv = vp[(size_t)j*HD + c];
            const float* pr = &st[j*32 + sub*16];
#pragma unroll
            for (int i = 0; i < 16; ++i) acc[i] += pr[i] * vv;
        }
        int b = bh / NH, nh = bh % NH;
#pragma unroll
        for (int i = 0; i < 16; ++i) {
            int qi = sub*16 + i;
            float val = acc[i]*inv_d[qi] + qt[c*32 + qi];
            out[((size_t)b*LQ + qbase + qi)*CDIM + nh*HD + c] = (bf16)val;
        }
    }
}

extern "C" void kernel_launch(void* const* d_in, const int* in_sizes, int n_in,
                              void* d_out, int out_size, void* d_ws, size_t ws_size,
                              hipStream_t stream) {
    const float* x      = (const float*)d_in[0];
    const float* qkv_w  = (const float*)d_in[1];
    const float* qkv_b  = (const float*)d_in[2];
    const float* proj_w = (const float*)d_in[3];
    const float* proj_b = (const float*)d_in[4];
    const float* pq_w   = (const float*)d_in[5];
    const float* pk_w   = (const float*)d_in[6];
    const float* pv_w   = (const float*)d_in[7];

    uint8_t* ws = (uint8_t*)d_ws;
    bf16*  x_bf     = (bf16*)(ws);                 // 38,535,168 el = 77,070,336 B
    bf16*  part_g   = (bf16*)(ws + 77070336);      // 38,535,168 el
    bf16*  wqkv_bf  = (bf16*)(ws + 154140672);     // 1,769,472 el
    bf16*  wproj_bf = (bf16*)(ws + 157679616);     // 589,824 el
    float* pool_q   = (float*)(ws + 158859264);    // 9,633,792 el
    float* pool_k   = (float*)(ws + 197394432);    // 602,112 el
    float* pool_v   = (float*)(ws + 199802880);    // 602,112 el
    bf16*  attn_o   = (bf16*)(ws + 202211328);     // 9,633,792 el
    // total ws use: 221,478,912 B

    cvt4<<<2048, 256, 0, stream>>>((const f4*)x, (bf16x4*)x_bf, 38535168/4);
    cvt4<<<1728, 256, 0, stream>>>((const f4*)qkv_w, (bf16x4*)wqkv_bf, 1769472/4);
    cvt4<<<576, 256, 0, stream>>>((const f4*)proj_w, (bf16x4*)wproj_bf, 589824/4);

    // per-part qkv GEMM (M=50176, N=768, K=768) + GELU epilogue, then pooling conv
    for (int p = 0; p < 3; ++p) {
        gemm_bt<0><<<dim3(392, 6), 256, 0, stream>>>(
            x_bf, wqkv_bf + (size_t)p*768*768, qkv_b + p*768, part_g, 50176, 768, 768);
        if (p == 0)
            dwconv<2, HP_Q, WP_Q><<<(16*LQ*HD + 255)/256, 256, 0, stream>>>(
                part_g, pq_w, pool_q, 16*LQ*HD);
        else if (p == 1)
            dwconv<8, HP_K, WP_K><<<(16*LK*HD + 255)/256, 256, 0, stream>>>(
                part_g, pk_w, pool_k, 16*LK*HD);
        else
            dwconv<8, HP_K, WP_K><<<(16*LK*HD + 255)/256, 256, 0, stream>>>(
                part_g, pv_w, pool_v, 16*LK*HD);
    }

    attn_kernel<<<BQ*NH*(LQ/32), 256, 0, stream>>>(pool_q, pool_k, pool_v, attn_o);

    // proj GEMM (M=12544, N=768, K=768), fp32 out + bias
    gemm_bt<1><<<dim3(98, 6), 256, 0, stream>>>(
        attn_o, wproj_bf, proj_b, d_out, 12544, 768, 768);
}

// Round 3
// 769.141 us; speedup vs baseline: 1.6301x; 1.6301x over previous
//
#include <hip/hip_runtime.h>
#include <cstdint>

#define NH 8
#define HD 96
#define CDIM 768
#define BQ 2
#define T0 8
#define H0 56
#define W0 56
#define L0 (T0*H0*W0)     // 25088
#define HP_Q 28
#define WP_Q 28
#define LQ (T0*HP_Q*WP_Q) // 6272
#define HP_K 7
#define WP_K 7
#define LK (T0*HP_K*WP_K) // 392
#define LKP 416           // kv padded to multiple of 32
#define SCALE 0.10206207261596577f

typedef __bf16 bf16;
typedef bf16 bf16x4 __attribute__((ext_vector_type(4)));
typedef bf16 bf16x8 __attribute__((ext_vector_type(8)));
typedef float f32x4 __attribute__((ext_vector_type(4)));
typedef float f4 __attribute__((ext_vector_type(4)));

#define GPTR(x) ((const __attribute__((address_space(1))) void*)(x))
#define LPTR(x) ((__attribute__((address_space(3))) void*)(x))

// ---------------- fp32 -> bf16 conversion ----------------
__global__ void cvt4(const f4* __restrict__ in, bf16x4* __restrict__ out, long n4) {
    long i = (long)blockIdx.x * blockDim.x + threadIdx.x;
    long stride = (long)gridDim.x * blockDim.x;
    for (; i < n4; i += stride) {
        f4 v = in[i];
        bf16x4 o;
        o.x = (bf16)v.x; o.y = (bf16)v.y; o.z = (bf16)v.z; o.w = (bf16)v.w;
        out[i] = o;
    }
}

// ---------------- MFMA GEMM: out[m,n] = sum_k A[m,k]*B[n,k] + bias[n] ----------------
// MODE 0: epilogue = GELU, scatter bf16 to [b*NH+nh][L0][HD]  (qkv part, N=768)
// MODE 1: epilogue = fp32 write to Out[m*N + n]                (proj)
template<int MODE>
__global__ __launch_bounds__(256) void gemm_bt(
    const bf16* __restrict__ A, const bf16* __restrict__ B,
    const float* __restrict__ bias, void* __restrict__ Out,
    int M, int N, int K)
{
    __shared__ bf16 As[128*32];
    __shared__ bf16 Bs[128*32];
    const int tid = threadIdx.x;
    const int lane = tid & 63;
    const int w = tid >> 6;
    const int wr = w >> 1, wc = w & 1;
    const long bm = blockIdx.x, bn = blockIdx.y;

    f32x4 acc[4][4];
#pragma unroll
    for (int i = 0; i < 4; ++i)
#pragma unroll
        for (int j = 0; j < 4; ++j) acc[i][j] = (f32x4){0.f,0.f,0.f,0.f};

    const int lrow = tid >> 2;        // 0..63
    const int lcol = (tid & 3) * 8;   // 0,8,16,24
    const bf16* Ag = A + (bm*128 + lrow)*(long)K + lcol;
    const bf16* Bg = B + (bn*128 + lrow)*(long)K + lcol;
    bf16* As0 = &As[lrow*32 + lcol];   // = As + tid*8 elements (tid*16 bytes): linear
    bf16* As1 = &As[(lrow+64)*32 + lcol];
    bf16* Bs0 = &Bs[lrow*32 + lcol];
    bf16* Bs1 = &Bs[(lrow+64)*32 + lcol];
    const int arow = lane & 15;
    const int akol = (lane >> 4) * 8;

    const int nkt = K / 32;
    for (int kt = 0; kt < nkt; ++kt) {
        __syncthreads();
        __builtin_amdgcn_global_load_lds(GPTR(Ag),          LPTR(As0), 16, 0, 0);
        __builtin_amdgcn_global_load_lds(GPTR(Ag + 64l*K),  LPTR(As1), 16, 0, 0);
        __builtin_amdgcn_global_load_lds(GPTR(Bg),          LPTR(Bs0), 16, 0, 0);
        __builtin_amdgcn_global_load_lds(GPTR(Bg + 64l*K),  LPTR(Bs1), 16, 0, 0);
        Ag += 32; Bg += 32;
        __syncthreads();
        bf16x8 af[4], bfr[4];
#pragma unroll
        for (int i = 0; i < 4; ++i) {
            af[i]  = *(const bf16x8*)&As[(wr*64 + i*16 + arow)*32 + akol];
            bfr[i] = *(const bf16x8*)&Bs[(wc*64 + i*16 + arow)*32 + akol];
        }
#pragma unroll
        for (int i = 0; i < 4; ++i)
#pragma unroll
            for (int j = 0; j < 4; ++j)
                acc[i][j] = __builtin_amdgcn_mfma_f32_16x16x32_bf16(af[i], bfr[j], acc[i][j], 0, 0, 0);
    }

    // epilogue: C/D layout col = lane&15, row = (lane>>4)*4 + r   [learn_hip m89]
#pragma unroll
    for (int i = 0; i < 4; ++i) {
        int row0 = (int)bm*128 + wr*64 + i*16 + ((lane>>4)<<2);
#pragma unroll
        for (int j = 0; j < 4; ++j) {
            int col = (int)bn*128 + wc*64 + j*16 + (lane & 15);
            float bcol = bias[col];
#pragma unroll
            for (int r = 0; r < 4; ++r) {
                float vacc = acc[i][j][r] + bcol;
                int m = row0 + r;
                if (MODE == 0) {
                    float g = 0.5f * vacc * (1.0f + erff(vacc * 0.7071067811865476f));
                    int b = m / L0, l = m % L0;
                    int nh = col / HD, c = col % HD;
                    ((bf16*)Out)[(((size_t)(b*NH + nh))*L0 + l)*HD + c] = (bf16)g;
                } else {
                    ((float*)Out)[(size_t)m*N + col] = vacc;
                }
            }
        }
    }
}

// ---------------- depthwise conv3d (k=3, pad=1, stride (1,ST,ST)), bf16 out ----------
// MODE 0: q  -> out[bh][l][c], LP = LQ (no pad)
// MODE 1: k  -> out[bh][l][c], LP = LKP, rows l>=LK zeroed
// MODE 2: v  -> out[bh][c][l] (transposed), LP = LKP, cols l>=LK zeroed
template<int ST, int HP, int WP, int MODE, int LP>
__global__ __launch_bounds__(256) void dwconv(
    const bf16* __restrict__ in, const float* __restrict__ w,
    bf16* __restrict__ out, int total)
{
    __shared__ float lw[27*HD];
    for (int i = threadIdx.x; i < 27*HD; i += 256) {
        int c = i / 27, tap = i % 27;
        lw[tap*HD + c] = w[i];
    }
    __syncthreads();
    int idx = blockIdx.x*256 + threadIdx.x;
    if (idx >= total) return;
    int c = idx % HD;
    int r = idx / HD;
    int l = r % LP;
    int bh = r / LP;
    size_t oidx;
    if (MODE == 2) oidx = ((size_t)bh*HD + c)*LP + l;
    else           oidx = ((size_t)bh*LP + l)*HD + c;
    if (MODE >= 1 && l >= LK) { out[oidx] = (bf16)0.f; return; }
    int xo = l % WP; int rr = l / WP;
    int yo = rr % HP;
    int to = rr / HP;
    const bf16* ip = in + (size_t)bh * L0 * HD;
    float acc = 0.f;
#pragma unroll
    for (int dt = 0; dt < 3; ++dt) {
        int t = to + dt - 1;
        if (t < 0 || t >= T0) continue;
#pragma unroll
        for (int dy = 0; dy < 3; ++dy) {
            int y = yo*ST + dy - 1;
            if (y < 0 || y >= H0) continue;
#pragma unroll
            for (int dx = 0; dx < 3; ++dx) {
                int x = xo*ST + dx - 1;
                if (x < 0 || x >= W0) continue;
                float val = (float)ip[((size_t)((t*H0 + y)*W0 + x))*HD + c];
                acc += lw[(dt*9 + dy*3 + dx)*HD + c] * val;
            }
        }
    }
    out[oidx] = (bf16)acc;
}

// ---------------- MFMA attention: block = (b,h) x 64 q rows, wave = 16 q rows -------
// q: [16][LQ][96] bf16;  k: [16][LKP][96] bf16 (rows>=LK zero);
// vt: [16][96][LKP] bf16 (cols>=LK zero);  out: [B][LQ][768] bf16
__global__ __launch_bounds__(256) void attn_mfma(
    const bf16* __restrict__ q, const bf16* __restrict__ k,
    const bf16* __restrict__ vt, bf16* __restrict__ out)
{
    const int tid = threadIdx.x;
    const int lane = tid & 63;
    const int w = tid >> 6;
    const int col = lane & 15;      // q index within wave tile / d index for VT frags
    const int g = lane >> 4;        // lane group 0..3
    const int blk = blockIdx.x;
    const int qblk = blk % (LQ/64);
    const int bh = blk / (LQ/64);
    const int q0 = qblk*64 + w*16;

    const bf16* Qp  = q  + ((size_t)bh*LQ + q0)*HD;
    const bf16* Kp  = k  + (size_t)bh*LKP*HD;
    const bf16* VTp = vt + (size_t)bh*HD*LKP;

    // Q^T B-fragments: B[k=d][col=q] -> lane holds Q[q0+col][c*32 + g*8 + j]
    bf16x8 qf[3];
#pragma unroll
    for (int c = 0; c < 3; ++c)
        qf[c] = *(const bf16x8*)&Qp[(size_t)col*HD + c*32 + g*8];

    f32x4 o[6];
#pragma unroll
    for (int t = 0; t < 6; ++t) o[t] = (f32x4){0.f,0.f,0.f,0.f};
    float lsum = 0.f;

    for (int kc = 0; kc < LKP/32; ++kc) {
        const int kvb = kc*32;
        // ---- scores: two 16-kv subtiles, S^T = mfma(K, Q^T): col=q, row=kv ----
        uint32_t P[2][2];   // [subtile][dword], packed bf16 pairs of exp(scores)
#pragma unroll
        for (int s = 0; s < 2; ++s) {
            f32x4 acc = (f32x4){0.f,0.f,0.f,0.f};
#pragma unroll
            for (int c = 0; c < 3; ++c) {
                bf16x8 kf = *(const bf16x8*)&Kp[(size_t)(kvb + s*16 + col)*HD + c*32 + g*8];
                acc = __builtin_amdgcn_mfma_f32_16x16x32_bf16(kf, qf[c], acc, 0, 0, 0);
            }
            bf16x4 pb;
#pragma unroll
            for (int r = 0; r < 4; ++r) {
                int kv = kvb + s*16 + g*4 + r;
                float p = (kv < LK) ? __expf(acc[r]*SCALE) : 0.f;
                lsum += p;
                pb[r] = (bf16)p;
            }
            union { bf16x4 v; uint32_t u[2]; } pk; pk.v = pb;
            P[s][0] = pk.u[0]; P[s][1] = pk.u[1];
        }
        // ---- redistribute P (rows g*4+r per subtile) -> B-frag rows g*8+j ----
        // target g0: H0=own X, H1=xor16(X); g1: H0=xor48(X), H1=xor32(X)
        //        g2: H0=xor32(Y), H1=xor48(Y); g3: H0=xor16(Y), H1=own Y
        // send sa=(g<2?Y:X) through xor32/xor48; send tb=(g<2?X:Y) through xor16.
        uint32_t sa0 = (g < 2) ? P[1][0] : P[0][0];
        uint32_t sa1 = (g < 2) ? P[1][1] : P[0][1];
        uint32_t tb0 = (g < 2) ? P[0][0] : P[1][0];
        uint32_t tb1 = (g < 2) ? P[0][1] : P[1][1];
        uint32_t R32_0 = (uint32_t)__shfl_xor((int)sa0, 32);
        uint32_t R32_1 = (uint32_t)__shfl_xor((int)sa1, 32);
        uint32_t R48_0 = (uint32_t)__shfl_xor((int)sa0, 48);
        uint32_t R48_1 = (uint32_t)__shfl_xor((int)sa1, 48);
        uint32_t R16_0 = (uint32_t)__shfl_xor((int)tb0, 16);
        uint32_t R16_1 = (uint32_t)__shfl_xor((int)tb1, 16);
        union { uint32_t u[4]; bf16x8 v; } pf;
        pf.u[0] = (g == 0) ? P[0][0] : (g == 1) ? R48_0 : (g == 2) ? R32_0 : R16_0;
        pf.u[1] = (g == 0) ? P[0][1] : (g == 1) ? R48_1 : (g == 2) ? R32_1 : R16_1;
        pf.u[2] = (g == 0) ? R16_0 : (g == 1) ? R32_0 : (g == 2) ? R48_0 : P[1][0];
        pf.u[3] = (g == 0) ? R16_1 : (g == 1) ? R32_1 : (g == 2) ? R48_1 : P[1][1];
        // ---- PV: O^T[d][q] += VT[d][kv-chunk] @ P^T[kv-chunk][q] ----
#pragma unroll
        for (int t = 0; t < 6; ++t) {
            bf16x8 vf = *(const bf16x8*)&VTp[(size_t)(t*16 + col)*LKP + kvb + g*8];
            o[t] = __builtin_amdgcn_mfma_f32_16x16x32_bf16(vf, pf.v, o[t], 0, 0, 0);
        }
    }

    // per-q denominator: sum partials across the 4 lane groups
    lsum += __shfl_xor(lsum, 16);
    lsum += __shfl_xor(lsum, 32);
    float inv = 1.f / lsum;

    const int b = bh >> 3, nh = bh & 7;
    size_t obase = ((size_t)b*LQ + q0 + col)*CDIM + (size_t)nh*HD;
#pragma unroll
    for (int t = 0; t < 6; ++t) {
        bf16x4 qres = *(const bf16x4*)&Qp[(size_t)col*HD + t*16 + g*4];
        bf16x4 ov;
#pragma unroll
        for (int r = 0; r < 4; ++r)
            ov[r] = (bf16)(o[t][r]*inv + (float)qres[r]);
        *(bf16x4*)&out[obase + t*16 + g*4] = ov;
    }
}

extern "C" void kernel_launch(void* const* d_in, const int* in_sizes, int n_in,
                              void* d_out, int out_size, void* d_ws, size_t ws_size,
                              hipStream_t stream) {
    const float* x      = (const float*)d_in[0];
    const float* qkv_w  = (const float*)d_in[1];
    const float* qkv_b  = (const float*)d_in[2];
    const float* proj_w = (const float*)d_in[3];
    const float* proj_b = (const float*)d_in[4];
    const float* pq_w   = (const float*)d_in[5];
    const float* pk_w   = (const float*)d_in[6];
    const float* pv_w   = (const float*)d_in[7];

    uint8_t* ws = (uint8_t*)d_ws;
    bf16*  x_bf     = (bf16*)(ws);                 // 77,070,336 B
    bf16*  part_g   = (bf16*)(ws + 77070336);      // 77,070,336 B
    bf16*  wqkv_bf  = (bf16*)(ws + 154140672);     // 3,538,944 B
    bf16*  wproj_bf = (bf16*)(ws + 157679616);     // 1,179,648 B
    bf16*  q_bf     = (bf16*)(ws + 158859264);     // 19,267,584 B [16][6272][96]
    bf16*  k_bf     = (bf16*)(ws + 178126848);     // 1,277,952 B  [16][416][96]
    bf16*  vt_bf    = (bf16*)(ws + 179404800);     // 1,277,952 B  [16][96][416]
    bf16*  attn_o   = (bf16*)(ws + 180682752);     // 19,267,584 B -> end 199,950,336

    cvt4<<<2048, 256, 0, stream>>>((const f4*)x, (bf16x4*)x_bf, 38535168/4);
    cvt4<<<1728, 256, 0, stream>>>((const f4*)qkv_w, (bf16x4*)wqkv_bf, 1769472/4);
    cvt4<<<576, 256, 0, stream>>>((const f4*)proj_w, (bf16x4*)wproj_bf, 589824/4);

    // per-part qkv GEMM (M=50176, N=768, K=768) + GELU epilogue, then pooling conv
    for (int p = 0; p < 3; ++p) {
        gemm_bt<0><<<dim3(392, 6), 256, 0, stream>>>(
            x_bf, wqkv_bf + (size_t)p*768*768, qkv_b + p*768, part_g, 50176, 768, 768);
        if (p == 0)
            dwconv<2, HP_Q, WP_Q, 0, LQ><<<(16*LQ*HD + 255)/256, 256, 0, stream>>>(
                part_g, pq_w, q_bf, 16*LQ*HD);
        else if (p == 1)
            dwconv<8, HP_K, WP_K, 1, LKP><<<(16*LKP*HD + 255)/256, 256, 0, stream>>>(
                part_g, pk_w, k_bf, 16*LKP*HD);
        else
            dwconv<8, HP_K, WP_K, 2, LKP><<<(16*LKP*HD + 255)/256, 256, 0, stream>>>(
                part_g, pv_w, vt_bf, 16*LKP*HD);
    }

    attn_mfma<<<16*(LQ/64), 256, 0, stream>>>(q_bf, k_bf, vt_bf, attn_o);

    // proj GEMM (M=12544, N=768, K=768), fp32 out + bias
    gemm_bt<1><<<dim3(98, 6), 256, 0, stream>>>(
        attn_o, wproj_bf, proj_b, d_out, 12544, 768, 768);
}

// Round 4
// 571.129 us; speedup vs baseline: 2.1953x; 1.3467x over previous
//
#include <hip/hip_runtime.h>
#include <cstdint>

#define NH 8
#define HD 96
#define CDIM 768
#define BQ 2
#define T0 8
#define H0 56
#define W0 56
#define L0 (T0*H0*W0)     // 25088
#define HP_Q 28
#define WP_Q 28
#define LQ (T0*HP_Q*WP_Q) // 6272
#define HP_K 7
#define WP_K 7
#define LK (T0*HP_K*WP_K) // 392
#define LKP 416           // kv padded to multiple of 32
#define SCALE 0.10206207261596577f

typedef __bf16 bf16;
typedef bf16 bf16x4 __attribute__((ext_vector_type(4)));
typedef bf16 bf16x8 __attribute__((ext_vector_type(8)));
typedef float f32x4 __attribute__((ext_vector_type(4)));
typedef float f4 __attribute__((ext_vector_type(4)));

#define GPTR(x) ((const __attribute__((address_space(1))) void*)(x))
#define LPTR(x) ((__attribute__((address_space(3))) void*)(x))

// ---------------- fp32 -> bf16 conversion ----------------
__global__ void cvt4(const f4* __restrict__ in, bf16x4* __restrict__ out, long n4) {
    long i = (long)blockIdx.x * blockDim.x + threadIdx.x;
    long stride = (long)gridDim.x * blockDim.x;
    for (; i < n4; i += stride) {
        f4 v = in[i];
        bf16x4 o;
        o.x = (bf16)v.x; o.y = (bf16)v.y; o.z = (bf16)v.z; o.w = (bf16)v.w;
        out[i] = o;
    }
}

// ---------------- MFMA GEMM: out[m,n] = sum_k A[m,k]*B[n,k] + bias[n] ----------------
// grid = (N/128, M/128): bn fastest so consecutive blocks share the A-tile (L2 reuse)
// MODE 0: epilogue = GELU, scatter bf16 to [part][b*NH+nh][L0][HD]  (qkv, N=768 or 2304)
// MODE 1: epilogue = fp32 write to Out[m*N + n]                     (proj)
template<int MODE>
__global__ __launch_bounds__(256) void gemm_bt(
    const bf16* __restrict__ A, const bf16* __restrict__ B,
    const float* __restrict__ bias, void* __restrict__ Out,
    int M, int N, int K)
{
    __shared__ bf16 As[128*32];
    __shared__ bf16 Bs[128*32];
    const int tid = threadIdx.x;
    const int lane = tid & 63;
    const int w = tid >> 6;
    const int wr = w >> 1, wc = w & 1;
    const long bn = blockIdx.x, bm = blockIdx.y;

    f32x4 acc[4][4];
#pragma unroll
    for (int i = 0; i < 4; ++i)
#pragma unroll
        for (int j = 0; j < 4; ++j) acc[i][j] = (f32x4){0.f,0.f,0.f,0.f};

    const int lrow = tid >> 2;        // 0..63
    const int lcol = (tid & 3) * 8;   // 0,8,16,24
    const bf16* Ag = A + (bm*128 + lrow)*(long)K + lcol;
    const bf16* Bg = B + (bn*128 + lrow)*(long)K + lcol;
    bf16* As0 = &As[lrow*32 + lcol];   // = As + tid*16 bytes: linear for global_load_lds
    bf16* As1 = &As[(lrow+64)*32 + lcol];
    bf16* Bs0 = &Bs[lrow*32 + lcol];
    bf16* Bs1 = &Bs[(lrow+64)*32 + lcol];
    const int arow = lane & 15;
    const int akol = (lane >> 4) * 8;

    const int nkt = K / 32;
    for (int kt = 0; kt < nkt; ++kt) {
        __syncthreads();
        __builtin_amdgcn_global_load_lds(GPTR(Ag),          LPTR(As0), 16, 0, 0);
        __builtin_amdgcn_global_load_lds(GPTR(Ag + 64l*K),  LPTR(As1), 16, 0, 0);
        __builtin_amdgcn_global_load_lds(GPTR(Bg),          LPTR(Bs0), 16, 0, 0);
        __builtin_amdgcn_global_load_lds(GPTR(Bg + 64l*K),  LPTR(Bs1), 16, 0, 0);
        Ag += 32; Bg += 32;
        __syncthreads();
        bf16x8 af[4], bfr[4];
#pragma unroll
        for (int i = 0; i < 4; ++i) {
            af[i]  = *(const bf16x8*)&As[(wr*64 + i*16 + arow)*32 + akol];
            bfr[i] = *(const bf16x8*)&Bs[(wc*64 + i*16 + arow)*32 + akol];
        }
#pragma unroll
        for (int i = 0; i < 4; ++i)
#pragma unroll
            for (int j = 0; j < 4; ++j)
                acc[i][j] = __builtin_amdgcn_mfma_f32_16x16x32_bf16(af[i], bfr[j], acc[i][j], 0, 0, 0);
    }

    // epilogue: C/D layout col = lane&15, row = (lane>>4)*4 + r   [learn_hip m89]
#pragma unroll
    for (int i = 0; i < 4; ++i) {
        int row0 = (int)bm*128 + wr*64 + i*16 + ((lane>>4)<<2);
#pragma unroll
        for (int j = 0; j < 4; ++j) {
            int col = (int)bn*128 + wc*64 + j*16 + (lane & 15);
            float bcol = bias[col];
#pragma unroll
            for (int r = 0; r < 4; ++r) {
                float vacc = acc[i][j][r] + bcol;
                int m = row0 + r;
                if (MODE == 0) {
                    float g = 0.5f * vacc * (1.0f + erff(vacc * 0.7071067811865476f));
                    int part = col / 768;
                    int c768 = col - part*768;
                    int b = m / L0, l = m % L0;
                    int nh = c768 / HD, c = c768 % HD;
                    bf16* outp = (bf16*)Out + (size_t)part * 16 * L0 * HD;
                    outp[(((size_t)(b*NH + nh))*L0 + l)*HD + c] = (bf16)g;
                } else {
                    ((float*)Out)[(size_t)m*N + col] = vacc;
                }
            }
        }
    }
}

// ---------------- depthwise conv3d (k=3, pad=1, stride (1,ST,ST)), bf16 out ----------
// thread = (bh, yo, xo, c8): computes all T0 'to' outputs for 8 channels.
// MODE 0: q  -> out[bh][l][c];  MODE 1: k -> out[bh][l][c] (LP rows, pad pre-zeroed)
// MODE 2: v  -> out[bh][c][l] (transposed; pad cols pre-zeroed)
template<int ST, int HP, int WP, int MODE, int LP>
__global__ __launch_bounds__(256) void dwconv2(
    const bf16* __restrict__ in, const float* __restrict__ w,
    bf16* __restrict__ out, int total)
{
    __shared__ float lw[27*HD];
    for (int i = threadIdx.x; i < 27*HD; i += 256) {
        int c = i / 27, tap = i % 27;
        lw[tap*HD + c] = w[i];
    }
    __syncthreads();
    int idx = blockIdx.x*256 + threadIdx.x;
    if (idx >= total) return;         // total = 16*HP*WP*12
    int c8 = idx % 12;
    int p = idx / 12;
    int xo = p % WP;
    int yo = (p / WP) % HP;
    int bh = p / (WP*HP);
    const bf16* ip = in + (size_t)bh * L0 * HD + c8*8;

    float acc[T0][8];
#pragma unroll
    for (int t = 0; t < T0; ++t)
#pragma unroll
        for (int j = 0; j < 8; ++j) acc[t][j] = 0.f;

#pragma unroll
    for (int dy = 0; dy < 3; ++dy) {
        int y = yo*ST + dy - 1;
        if ((unsigned)y >= (unsigned)H0) continue;
#pragma unroll
        for (int dx = 0; dx < 3; ++dx) {
            int x = xo*ST + dx - 1;
            if ((unsigned)x >= (unsigned)W0) continue;
            float wreg[3][8];
#pragma unroll
            for (int dt = 0; dt < 3; ++dt)
#pragma unroll
                for (int j = 0; j < 8; ++j)
                    wreg[dt][j] = lw[(dt*9 + dy*3 + dx)*HD + c8*8 + j];
            const bf16* colp = ip + ((size_t)(y*W0 + x))*HD;
#pragma unroll
            for (int t = 0; t < T0; ++t) {
                bf16x8 v = *(const bf16x8*)(colp + (size_t)t*H0*W0*HD);
                float f[8];
#pragma unroll
                for (int j = 0; j < 8; ++j) f[j] = (float)v[j];
#pragma unroll
                for (int dt = 0; dt < 3; ++dt) {
                    int to = t - dt + 1;        // input t feeds outputs t-1,t,t+1
                    if (to < 0 || to >= T0) continue;
#pragma unroll
                    for (int j = 0; j < 8; ++j)
                        acc[to][j] += wreg[dt][j] * f[j];
                }
            }
        }
    }

#pragma unroll
    for (int to = 0; to < T0; ++to) {
        int l = (to*HP + yo)*WP + xo;
        if (MODE == 2) {
#pragma unroll
            for (int j = 0; j < 8; ++j)
                out[((size_t)bh*HD + c8*8 + j)*LP + l] = (bf16)acc[to][j];
        } else {
            bf16x8 ov;
#pragma unroll
            for (int j = 0; j < 8; ++j) ov[j] = (bf16)acc[to][j];
            *(bf16x8*)&out[((size_t)bh*LP + l)*HD + c8*8] = ov;
        }
    }
}

// ---------------- MFMA attention: block = (b,h) x 64 q rows, wave = 16 q rows -------
__global__ __launch_bounds__(256) void attn_mfma(
    const bf16* __restrict__ q, const bf16* __restrict__ k,
    const bf16* __restrict__ vt, bf16* __restrict__ out)
{
    const int tid = threadIdx.x;
    const int lane = tid & 63;
    const int w = tid >> 6;
    const int col = lane & 15;
    const int g = lane >> 4;
    const int blk = blockIdx.x;
    const int qblk = blk % (LQ/64);
    const int bh = blk / (LQ/64);
    const int q0 = qblk*64 + w*16;

    const bf16* Qp  = q  + ((size_t)bh*LQ + q0)*HD;
    const bf16* Kp  = k  + (size_t)bh*LKP*HD;
    const bf16* VTp = vt + (size_t)bh*HD*LKP;

    bf16x8 qf[3];
#pragma unroll
    for (int c = 0; c < 3; ++c)
        qf[c] = *(const bf16x8*)&Qp[(size_t)col*HD + c*32 + g*8];

    f32x4 o[6];
#pragma unroll
    for (int t = 0; t < 6; ++t) o[t] = (f32x4){0.f,0.f,0.f,0.f};
    float lsum = 0.f;

    for (int kc = 0; kc < LKP/32; ++kc) {
        const int kvb = kc*32;
        uint32_t P[2][2];
#pragma unroll
        for (int s = 0; s < 2; ++s) {
            f32x4 acc = (f32x4){0.f,0.f,0.f,0.f};
#pragma unroll
            for (int c = 0; c < 3; ++c) {
                bf16x8 kf = *(const bf16x8*)&Kp[(size_t)(kvb + s*16 + col)*HD + c*32 + g*8];
                acc = __builtin_amdgcn_mfma_f32_16x16x32_bf16(kf, qf[c], acc, 0, 0, 0);
            }
            bf16x4 pb;
#pragma unroll
            for (int r = 0; r < 4; ++r) {
                int kv = kvb + s*16 + g*4 + r;
                float p = (kv < LK) ? __expf(acc[r]*SCALE) : 0.f;
                lsum += p;
                pb[r] = (bf16)p;
            }
            union { bf16x4 v; uint32_t u[2]; } pk; pk.v = pb;
            P[s][0] = pk.u[0]; P[s][1] = pk.u[1];
        }
        uint32_t sa0 = (g < 2) ? P[1][0] : P[0][0];
        uint32_t sa1 = (g < 2) ? P[1][1] : P[0][1];
        uint32_t tb0 = (g < 2) ? P[0][0] : P[1][0];
        uint32_t tb1 = (g < 2) ? P[0][1] : P[1][1];
        uint32_t R32_0 = (uint32_t)__shfl_xor((int)sa0, 32);
        uint32_t R32_1 = (uint32_t)__shfl_xor((int)sa1, 32);
        uint32_t R48_0 = (uint32_t)__shfl_xor((int)sa0, 48);
        uint32_t R48_1 = (uint32_t)__shfl_xor((int)sa1, 48);
        uint32_t R16_0 = (uint32_t)__shfl_xor((int)tb0, 16);
        uint32_t R16_1 = (uint32_t)__shfl_xor((int)tb1, 16);
        union { uint32_t u[4]; bf16x8 v; } pf;
        pf.u[0] = (g == 0) ? P[0][0] : (g == 1) ? R48_0 : (g == 2) ? R32_0 : R16_0;
        pf.u[1] = (g == 0) ? P[0][1] : (g == 1) ? R48_1 : (g == 2) ? R32_1 : R16_1;
        pf.u[2] = (g == 0) ? R16_0 : (g == 1) ? R32_0 : (g == 2) ? R48_0 : P[1][0];
        pf.u[3] = (g == 0) ? R16_1 : (g == 1) ? R32_1 : (g == 2) ? R48_1 : P[1][1];
#pragma unroll
        for (int t = 0; t < 6; ++t) {
            bf16x8 vf = *(const bf16x8*)&VTp[(size_t)(t*16 + col)*LKP + kvb + g*8];
            o[t] = __builtin_amdgcn_mfma_f32_16x16x32_bf16(vf, pf.v, o[t], 0, 0, 0);
        }
    }

    lsum += __shfl_xor(lsum, 16);
    lsum += __shfl_xor(lsum, 32);
    float inv = 1.f / lsum;

    const int b = bh >> 3, nh = bh & 7;
    size_t obase = ((size_t)b*LQ + q0 + col)*CDIM + (size_t)nh*HD;
#pragma unroll
    for (int t = 0; t < 6; ++t) {
        bf16x4 qres = *(const bf16x4*)&Qp[(size_t)col*HD + t*16 + g*4];
        bf16x4 ov;
#pragma unroll
        for (int r = 0; r < 4; ++r)
            ov[r] = (bf16)(o[t][r]*inv + (float)qres[r]);
        *(bf16x4*)&out[obase + t*16 + g*4] = ov;
    }
}

extern "C" void kernel_launch(void* const* d_in, const int* in_sizes, int n_in,
                              void* d_out, int out_size, void* d_ws, size_t ws_size,
                              hipStream_t stream) {
    const float* x      = (const float*)d_in[0];
    const float* qkv_w  = (const float*)d_in[1];
    const float* qkv_b  = (const float*)d_in[2];
    const float* proj_w = (const float*)d_in[3];
    const float* proj_b = (const float*)d_in[4];
    const float* pq_w   = (const float*)d_in[5];
    const float* pk_w   = (const float*)d_in[6];
    const float* pv_w   = (const float*)d_in[7];

    uint8_t* ws = (uint8_t*)d_ws;
    const bool fused = ws_size >= 355000000ull;

    bf16 *x_bf, *qkv_g, *wqkv_bf, *wproj_bf, *q_bf, *k_bf, *vt_bf, *attn_o;
    x_bf = (bf16*)ws;                              // 77,070,336 B
    if (fused) {
        qkv_g    = (bf16*)(ws +  77070336);        // 231,211,008 B: [3][16][L0][96]
        wqkv_bf  = (bf16*)(ws + 308281344);        // 3,538,944 B
        wproj_bf = (bf16*)(ws + 311820288);        // 1,179,648 B
        q_bf     = (bf16*)(ws + 312999936);        // 19,267,584 B [16][6272][96]
        k_bf     = (bf16*)(ws + 332267520);        // 1,277,952 B  [16][416][96]
        vt_bf    = (bf16*)(ws + 333545472);        // 1,277,952 B  [16][96][416]
        attn_o   = (bf16*)(ws + 334823424);        // 19,267,584 B -> end 354,091,008
    } else {
        qkv_g    = (bf16*)(ws +  77070336);        // 77,070,336 B (one part at a time)
        wqkv_bf  = (bf16*)(ws + 154140672);
        wproj_bf = (bf16*)(ws + 157679616);
        q_bf     = (bf16*)(ws + 158859264);
        k_bf     = (bf16*)(ws + 178126848);
        vt_bf    = (bf16*)(ws + 179404800);
        attn_o   = (bf16*)(ws + 180682752);        // -> end 199,950,336
    }

    hipMemsetAsync(k_bf, 0, 1277952, stream);
    hipMemsetAsync(vt_bf, 0, 1277952, stream);

    cvt4<<<2048, 256, 0, stream>>>((const f4*)x, (bf16x4*)x_bf, 38535168/4);
    cvt4<<<1728, 256, 0, stream>>>((const f4*)qkv_w, (bf16x4*)wqkv_bf, 1769472/4);
    cvt4<<<576, 256, 0, stream>>>((const f4*)proj_w, (bf16x4*)wproj_bf, 589824/4);

    const size_t PART = (size_t)16*L0*HD;
    if (fused) {
        gemm_bt<0><<<dim3(18, 392), 256, 0, stream>>>(
            x_bf, wqkv_bf, qkv_b, qkv_g, 50176, 2304, 768);
        dwconv2<2, HP_Q, WP_Q, 0, LQ><<<588, 256, 0, stream>>>(
            qkv_g, pq_w, q_bf, 16*HP_Q*WP_Q*12);
        dwconv2<8, HP_K, WP_K, 1, LKP><<<37, 256, 0, stream>>>(
            qkv_g + PART, pk_w, k_bf, 16*HP_K*WP_K*12);
        dwconv2<8, HP_K, WP_K, 2, LKP><<<37, 256, 0, stream>>>(
            qkv_g + 2*PART, pv_w, vt_bf, 16*HP_K*WP_K*12);
    } else {
        for (int p = 0; p < 3; ++p) {
            gemm_bt<0><<<dim3(6, 392), 256, 0, stream>>>(
                x_bf, wqkv_bf + (size_t)p*768*768, qkv_b + p*768, qkv_g, 50176, 768, 768);
            if (p == 0)
                dwconv2<2, HP_Q, WP_Q, 0, LQ><<<588, 256, 0, stream>>>(
                    qkv_g, pq_w, q_bf, 16*HP_Q*WP_Q*12);
            else if (p == 1)
                dwconv2<8, HP_K, WP_K, 1, LKP><<<37, 256, 0, stream>>>(
                    qkv_g, pk_w, k_bf, 16*HP_K*WP_K*12);
            else
                dwconv2<8, HP_K, WP_K, 2, LKP><<<37, 256, 0, stream>>>(
                    qkv_g, pv_w, vt_bf, 16*HP_K*WP_K*12);
        }
    }

    attn_mfma<<<16*(LQ/64), 256, 0, stream>>>(q_bf, k_bf, vt_bf, attn_o);

    gemm_bt<1><<<dim3(6, 98), 256, 0, stream>>>(
        attn_o, wproj_bf, proj_b, d_out, 12544, 768, 768);
}